// Round 8
// baseline (229.856 us; speedup 1.0000x reference)
//
#include <hip/hip_runtime.h>
#include <hip/hip_bf16.h>

#define NB 32
#define NC 128
#define NH 56
#define NW 56
#define HP 58
#define WP 58
#define KK 1152
#define NPOS 3136                         // 56*56
#define XT_BYTES (NB * HP * WP * NC * 2)  // 27,557,888
#define AW_OFF XT_BYTES

typedef __attribute__((ext_vector_type(8))) short s16x8;
typedef __attribute__((ext_vector_type(4))) float f32x4;
typedef unsigned int u32;

__device__ __forceinline__ unsigned short f2bf(float f) {
    union { float f; unsigned int u; } v; v.f = f;
    unsigned int u = v.u + 0x7fffu + ((v.u >> 16) & 1u);
    return (unsigned short)(u >> 16);
}

__device__ __forceinline__ u32 pk2(float a, float b) {
    __hip_bfloat162 h = __float22bfloat162_rn(float2{a, b});
    u32 r; __builtin_memcpy(&r, &h, 4); return r;
}

__device__ __forceinline__ void gld16(const void* g, void* l) {
    __builtin_amdgcn_global_load_lds(
        (const __attribute__((address_space(1))) u32*)g,
        (__attribute__((address_space(3))) u32*)l, 16, 0, 0);
}

// ---- fused prologue: blocks [0,1792) transpose x; [1792,4096) permute w ----
// xpose: [B,C,56,56]f32 -> x_t [B,58,58,C]bf16 (padded, halo zeroed).
// LDS tile layout: u32 tile[xp][cp] (cp = channel pair), row pitch 65 u32
// (padding -> <=2-way banks both phases). Phase 2: ds_read_b128 + b128 store.
__global__ void k_pro(const float* __restrict__ x, const float* __restrict__ w,
                      unsigned short* __restrict__ xt, unsigned short* __restrict__ aw) {
    int blk = blockIdx.x;
    int tid = threadIdx.x;
    if (blk >= 1792) {
        int idx = (blk - 1792) * 256 + tid;   // 589824 total
        if (idx < 512 * KK) {
            int j = idx & 7, lane = (idx >> 3) & 63, mt = (idx >> 9) & 31, s = idx >> 14;
            int m = mt * 16 + (lane & 15);
            int kg = s * 32 + (lane >> 4) * 8 + j;
            int g = kg >> 7, ic = kg & 127;
            aw[idx] = f2bf(w[(m * 128 + ic) * 9 + g]);
        }
        return;
    }
    __shared__ u32 tile[56 * 65];             // [xp][cp], pitch 65
    int b = blk / NH, y = blk % NH;
    const float* xb = x + (size_t)b * (NC * NPOS) + y * NW;
#pragma unroll
    for (int p = 0; p < 4; ++p) {
        int idx = p * 256 + tid;              // 896 = 64 c-pairs x 14 x4-groups
        if (idx < 896) {
            int cp = idx / 14, i = idx - cp * 14;
            float4 va = *(const float4*)(xb + (2 * cp) * NPOS + i * 4);
            float4 vb = *(const float4*)(xb + (2 * cp + 1) * NPOS + i * 4);
            u32* tp = &tile[(i * 4) * 65 + cp];
            tp[0]       = pk2(va.x, vb.x);
            tp[65]      = pk2(va.y, vb.y);
            tp[130]     = pk2(va.z, vb.z);
            tp[195]     = pk2(va.w, vb.w);
        }
    }
    __syncthreads();
    unsigned short* xrow = xt + ((size_t)(b * HP + y + 1) * WP + 1) * NC;
#pragma unroll
    for (int p = 0; p < 4; ++p) {
        int idx = p * 256 + tid;              // 896 = 56 xp x 16 u32-quads
        if (idx < 896) {
            int xp = idx >> 4, q = idx & 15;
            uint4 v = *(const uint4*)&tile[xp * 65 + q * 4];
            *(uint4*)(xrow + xp * NC + q * 8) = v;
        }
    }
    // halo: left/right columns of this row
    if (tid < 128) {
        xt[((size_t)(b * HP + y + 1) * WP + 0) * NC + tid] = 0;
        xt[((size_t)(b * HP + y + 1) * WP + 57) * NC + tid] = 0;
    }
    if (y == 0) {
        unsigned short* r0 = xt + (size_t)(b * HP + 0) * WP * NC;
        for (int i = tid; i < WP * NC; i += 256) r0[i] = 0;
    }
    if (y == 55) {
        unsigned short* r57 = xt + (size_t)(b * HP + 57) * WP * NC;
        for (int i = tid; i < WP * NC; i += 256) r57[i] = 0;
    }
}

// ---- main: fused implicit-GEMM conv + softmax rank combine + biases ----
// 8 waves, M=512 (4 ranks x 128 ch), N=112 (2 image rows), K=1152.
// 9 barrier-stages of K=128 = one 3x3 filter tap each. A: global->VGPR
// ping-pong. B: shared LDS 2x28KB dbuf via gld16, XOR-16 chunk swizzle.
// PHASE STAGGER ph=(wv>>2)*2: waves w and w+4 share a SIMD (round-robin
// mapping) and get opposite K32 sub-slice rotation -> one wave's LDS/L2
// burst overlaps the SIMD-mate's MFMA burst.
__global__ void __launch_bounds__(512, 2) k_main(
    const unsigned short* __restrict__ xt, const unsigned short* __restrict__ aw,
    const float* __restrict__ cwr, const float* __restrict__ cwc,
    const float* __restrict__ brow, const float* __restrict__ bcol,
    const float* __restrict__ bch, float* __restrict__ out) {
    __shared__ __align__(16) unsigned char ldsB[2][28672];   // 112 rows x 256B

    const int tid = threadIdx.x;
    const int lane = tid & 63;
    const int wv = tid >> 6;
    const int l15 = lane & 15, quad = lane >> 4;
    const int ph = (wv >> 2) * 2;           // anti-phase for SIMD-mates
    const int blk = blockIdx.x;
    const int b = blk / 28;
    const int tile0 = (blk - b * 28) * 112;

    const unsigned char* xt_b = (const unsigned char*)xt + (size_t)b * (HP * WP * NC * 2);
    const unsigned char* gA = (const unsigned char*)aw + wv * 1024 + lane * 16;

    // B staging: wave wv (0..6) stages rows wv*16..+15; gld16 #h covers 4 rows
    // (h*4 + lane>>4), phys chunk lane&15, global chunk (lane&15)^(row&15).
    const unsigned char* gB[4];
    if (wv < 7) {
#pragma unroll
        for (int h = 0; h < 4; ++h) {
            int rl = h * 4 + (lane >> 4);
            int row = wv * 16 + rl;
            int pos = tile0 + row;
            int yy = pos / 56, xx = pos - yy * 56;
            int c = (lane & 15) ^ rl;
            gB[h] = xt_b + ((yy + 1) * WP + (xx + 1)) * (NC * 2) + c * 16;
        }
    }

    s16x8 Areg[2][4];          // [pingpong][rank]
    f32x4 acc[4][7] = {};      // [rank][ntile]

    auto aload = [&](int s32, int pp) {
#pragma unroll
        for (int r = 0; r < 4; ++r)
            Areg[pp][r] = *(const s16x8*)(gA + s32 * 32768 + r * 8192);
    };
    auto bissue = [&](int st, int buf) {
        if (wv < 7) {
            int dy = (st * 11) >> 5, dx = st - dy * 3;
            int off = ((dy - 1) * WP + (dx - 1)) * (NC * 2);
            unsigned char* L = &ldsB[buf][wv * 4096];
#pragma unroll
            for (int h = 0; h < 4; ++h) gld16(gB[h] + off, L + h * 1024);
        }
    };

    aload(ph, 0);              // first slice in this wave's rotated sequence
    bissue(0, 0);
    __syncthreads();

    for (int st = 0; st < 9; ++st) {
        const int cur = st & 1;
        if (st < 8) bissue(st + 1, cur ^ 1);
        const unsigned char* L = &ldsB[cur][0];
#pragma unroll
        for (int j = 0; j < 4; ++j) {
            const int kkw = (j + ph) & 3;      // this wave's sub-slice this beat
            // prefetch next slice in this wave's own sequence
            if (!(st == 8 && j == 3)) {
                int nslice = (j < 3) ? st * 4 + (((j + 1) + ph) & 3)
                                     : (st + 1) * 4 + ph;
                aload(nslice, (j + 1) & 1);
            }
            s16x8 bf[7];
#pragma unroll
            for (int t = 0; t < 7; ++t)
                bf[t] = *(const s16x8*)(L + (t * 16 + l15) * 256
                                          + (((kkw * 4 + quad) ^ l15) << 4));
#pragma unroll
            for (int r = 0; r < 4; ++r)
#pragma unroll
                for (int t = 0; t < 7; ++t)
                    acc[r][t] = __builtin_amdgcn_mfma_f32_16x16x32_bf16(
                        Areg[j & 1][r], bf[t], acc[r][t], 0, 0, 0);
        }
        __syncthreads();
    }

    // epilogue: inline softmax over rank + combine + biases, fp32 store
#pragma unroll
    for (int t = 0; t < 7; ++t) {
        int pos = tile0 + t * 16 + l15;
        int yy = pos / 56, xx = pos - yy * 56;
        float v0 = cwr[yy]       + cwc[xx];
        float v1 = cwr[56 + yy]  + cwc[56 + xx];
        float v2 = cwr[112 + yy] + cwc[112 + xx];
        float v3 = cwr[168 + yy] + cwc[168 + xx];
        float mx = fmaxf(fmaxf(v0, v1), fmaxf(v2, v3));
        float e0 = __expf(v0 - mx), e1 = __expf(v1 - mx);
        float e2 = __expf(v2 - mx), e3 = __expf(v3 - mx);
        float inv = 1.0f / (e0 + e1 + e2 + e3);
        float c0 = e0 * inv, c1 = e1 * inv, c2 = e2 * inv, c3 = e3 * inv;
        float rb = brow[yy] + bcol[xx];
#pragma unroll
        for (int r = 0; r < 4; ++r) {
            int ch = wv * 16 + quad * 4 + r;
            float v = acc[0][t][r] * c0 + acc[1][t][r] * c1
                    + acc[2][t][r] * c2 + acc[3][t][r] * c3;
            out[((size_t)b * NC + ch) * NPOS + pos] = v + bch[ch] + rb;
        }
    }
}

extern "C" void kernel_launch(void* const* d_in, const int* in_sizes, int n_in,
                              void* d_out, int out_size, void* d_ws, size_t ws_size,
                              hipStream_t stream) {
    const float* x    = (const float*)d_in[0];
    const float* w    = (const float*)d_in[1];
    const float* cwr  = (const float*)d_in[2];
    const float* cwc  = (const float*)d_in[3];
    const float* brow = (const float*)d_in[4];
    const float* bcol = (const float*)d_in[5];
    const float* bch  = (const float*)d_in[6];
    float* out = (float*)d_out;

    unsigned char* ws = (unsigned char*)d_ws;
    unsigned short* xt = (unsigned short*)ws;
    unsigned short* aw = (unsigned short*)(ws + AW_OFF);

    k_pro<<<4096, 256, 0, stream>>>(x, w, xt, aw);   // xpose + wconv fused
    k_main<<<NB * 28, 512, 0, stream>>>(xt, aw, cwr, cwc, brow, bcol, bch, out);
}